// Round 1
// baseline (248.984 us; speedup 1.0000x reference)
//
#include <hip/hip_runtime.h>

// IntegerNeuron: T-step integrate-fire scan over [T,B,C,H,W].
// T=8, B=32, C=128, H=32, W=32. Memory-bound: 128 MiB in + 128 MiB out.
//
// Numerics: must be bit-exact vs the fp32 reference (hard threshold on mem).
// Reference op order:
//   drive = x * tau
//   mem   = (mem + drive) + bias_scaled
//   spike = mem >= vth_scaled
//   mem   = mem - spike * vth_scaled
// tau == 4.0 (power of two) => x*tau exact => FMA contraction of (mem + x*tau)
// is bit-identical. No reassociation at -O3 without -ffast-math.
// jnp.round == half-to-even == rintf.
//
// R1 changes vs 24-VGPR baseline (85 us/dispatch, 2.37 TB/s = 29% of peak):
//  - Preload all 8 timesteps into registers BEFORE the scan: baseline compiler
//    kept a load->waitcnt->store serial loop (VGPR=24 proves no hoisting);
//    this gives 8 loads in flight per wave instead of ~1.
//  - Non-temporal output stores: output writes were evicting the input from
//    the 256 MiB L3 (FETCH was 64 MiB ~ half the input). nt stores keep the
//    input resident across bench iterations.
//  - c = blockIdx.x % NC is wave-uniform (one (b,c) plane per 256-thread
//    block) -> scalar loads for prev_scale/prev_bias, bs/vs in SGPRs.

typedef float f4 __attribute__((ext_vector_type(4)));

constexpr int T_STEPS = 8;
constexpr int NB = 32, NC = 128, NH = 32, NW = 32;
constexpr int NSP = NB * NC * NH * NW;   // 4,194,304 spatial positions
constexpr int N4  = NSP / 4;             // 1,048,576 float4 positions
constexpr int HW4 = (NH * NW) / 4;       // 256 float4 per (b,c) plane == blockDim

__global__ __launch_bounds__(256) void IntegerNeuron_84842783965742_kernel(
    const f4*    __restrict__ x,            // [T, B, C, H, W] as float4
    const float* __restrict__ prev_scale,   // [C]
    const float* __restrict__ prev_bias,    // [C]
    const float* __restrict__ vth,          // scalar
    const int*   __restrict__ tau,          // scalar int
    const int*   __restrict__ is_first,     // scalar int
    f4*          __restrict__ out)          // [T, B, C, H, W] as float4
{
    const int i = blockIdx.x * blockDim.x + threadIdx.x;   // float4 index
    const int c = blockIdx.x % NC;  // uniform per block: blockDim == HW4, so
                                    // each block is exactly one (b,c) plane.

    const float tau_f = (float)tau[0];
    const float denom = prev_scale[c] + 1e-12f;
    const float bs = rintf(prev_bias[c] * tau_f / denom);  // bias_scaled[c]
    const float vs = rintf(vth[0] * tau_f / denom);        // vth_scaled[c]
    const float mul = is_first[0] ? 1.0f : tau_f;          // drive multiplier

    // --- Preload all T timesteps: 8 independent global loads in flight. ---
    f4 xv[T_STEPS];
    #pragma unroll
    for (int t = 0; t < T_STEPS; ++t) {
        xv[t] = x[(size_t)t * N4 + i];
    }

    float m0 = 0.0f, m1 = 0.0f, m2 = 0.0f, m3 = 0.0f;      // mem in VGPRs

    #pragma unroll
    for (int t = 0; t < T_STEPS; ++t) {
        // mem = (mem + x*tau) + bias_scaled  — matches reference association.
        m0 = (m0 + xv[t].x * mul) + bs;
        m1 = (m1 + xv[t].y * mul) + bs;
        m2 = (m2 + xv[t].z * mul) + bs;
        m3 = (m3 + xv[t].w * mul) + bs;

        f4 sp;
        sp.x = (m0 >= vs) ? 1.0f : 0.0f;
        sp.y = (m1 >= vs) ? 1.0f : 0.0f;
        sp.z = (m2 >= vs) ? 1.0f : 0.0f;
        sp.w = (m3 >= vs) ? 1.0f : 0.0f;

        // soft reset: spike and vs are integer-valued, product exact.
        m0 -= sp.x * vs;
        m1 -= sp.y * vs;
        m2 -= sp.z * vs;
        m3 -= sp.w * vs;

        // Non-temporal: output is write-once, never re-read by this kernel;
        // keep it out of L2/L3 so the input stays cache-resident.
        __builtin_nontemporal_store(sp, &out[(size_t)t * N4 + i]);
    }
}

extern "C" void kernel_launch(void* const* d_in, const int* in_sizes, int n_in,
                              void* d_out, int out_size, void* d_ws, size_t ws_size,
                              hipStream_t stream) {
    const f4*    x          = (const f4*)d_in[0];
    const float* prev_scale = (const float*)d_in[1];
    const float* prev_bias  = (const float*)d_in[2];
    const float* vth        = (const float*)d_in[3];
    const int*   tau        = (const int*)d_in[4];
    const int*   is_first   = (const int*)d_in[5];
    f4*          out        = (f4*)d_out;

    dim3 block(256);
    dim3 grid(N4 / 256);   // 4096 blocks
    IntegerNeuron_84842783965742_kernel<<<grid, block, 0, stream>>>(
        x, prev_scale, prev_bias, vth, tau, is_first, out);
}

// Round 2
// 248.092 us; speedup vs baseline: 1.0036x; 1.0036x over previous
//
#include <hip/hip_runtime.h>

// IntegerNeuron: T-step integrate-fire scan over [T,B,C,H,W].
// T=8, B=32, C=128, H=32, W=32. Memory-bound: 128 MiB in + 128 MiB out.
//
// Numerics: must be bit-exact vs the fp32 reference (hard threshold on mem).
// Reference op order:
//   drive = x * tau
//   mem   = (mem + drive) + bias_scaled
//   spike = mem >= vth_scaled
//   mem   = mem - spike * vth_scaled
// tau == 4.0 (power of two) => x*tau exact => FMA contraction of (mem + x*tau)
// is bit-identical. No reassociation at -O3 without -ffast-math.
// jnp.round == half-to-even == rintf.
//
// R2 changes:
//  - R1's preload was DEFEATED by the scheduler (VGPR stayed 24 => loads were
//    sunk back next to their uses => still 1 memory op in flight per wave).
//    Now the preload is pinned: a single asm volatile with all 8 float4s as
//    "+v" operands forces every load to issue and complete BEFORE any compute.
//    sched_barrier(0) blocks residual motion. This is the latency fix:
//    8 loads in flight per wave instead of ~1.
//  - Reverted R1's nontemporal stores: measured 85->92.5 us with FETCH_SIZE
//    unchanged (no L3 residency benefit, pure cost).
//  - Kept uniform-c scalar path (one (b,c) plane per block).

typedef float f4 __attribute__((ext_vector_type(4)));

constexpr int T_STEPS = 8;
constexpr int NB = 32, NC = 128, NH = 32, NW = 32;
constexpr int NSP = NB * NC * NH * NW;   // 4,194,304 spatial positions
constexpr int N4  = NSP / 4;             // 1,048,576 float4 positions
constexpr int HW4 = (NH * NW) / 4;       // 256 float4 per (b,c) plane == blockDim

__global__ __launch_bounds__(256) void IntegerNeuron_84842783965742_kernel(
    const f4*    __restrict__ x,            // [T, B, C, H, W] as float4
    const float* __restrict__ prev_scale,   // [C]
    const float* __restrict__ prev_bias,    // [C]
    const float* __restrict__ vth,          // scalar
    const int*   __restrict__ tau,          // scalar int
    const int*   __restrict__ is_first,     // scalar int
    f4*          __restrict__ out)          // [T, B, C, H, W] as float4
{
    const int i = blockIdx.x * blockDim.x + threadIdx.x;   // float4 index
    const int c = blockIdx.x % NC;  // uniform per block: blockDim == HW4, so
                                    // each block is exactly one (b,c) plane.

    const float tau_f = (float)tau[0];
    const float denom = prev_scale[c] + 1e-12f;
    const float bs = rintf(prev_bias[c] * tau_f / denom);  // bias_scaled[c]
    const float vs = rintf(vth[0] * tau_f / denom);        // vth_scaled[c]
    const float mul = is_first[0] ? 1.0f : tau_f;          // drive multiplier

    // --- Preload all T timesteps: 8 independent global loads in flight. ---
    f4 x0 = x[(size_t)0 * N4 + i];
    f4 x1 = x[(size_t)1 * N4 + i];
    f4 x2 = x[(size_t)2 * N4 + i];
    f4 x3 = x[(size_t)3 * N4 + i];
    f4 x4 = x[(size_t)4 * N4 + i];
    f4 x5 = x[(size_t)5 * N4 + i];
    f4 x6 = x[(size_t)6 * N4 + i];
    f4 x7 = x[(size_t)7 * N4 + i];

    // Pin: one asm statement reading+writing ALL eight vectors. The scheduler
    // cannot sink any load below this point, and cannot hoist any compute
    // above it — every load must be issued (and completed) first. This is
    // what #pragma unroll preloading failed to guarantee (R1: VGPR stayed 24).
    asm volatile("" : "+v"(x0), "+v"(x1), "+v"(x2), "+v"(x3),
                      "+v"(x4), "+v"(x5), "+v"(x6), "+v"(x7));
    __builtin_amdgcn_sched_barrier(0);

    float m0 = 0.0f, m1 = 0.0f, m2 = 0.0f, m3 = 0.0f;      // mem in VGPRs

    f4 xv;
    #pragma unroll
    for (int t = 0; t < T_STEPS; ++t) {
        switch (t) {
            case 0: xv = x0; break;
            case 1: xv = x1; break;
            case 2: xv = x2; break;
            case 3: xv = x3; break;
            case 4: xv = x4; break;
            case 5: xv = x5; break;
            case 6: xv = x6; break;
            default: xv = x7; break;
        }

        // mem = (mem + x*tau) + bias_scaled  — matches reference association.
        m0 = (m0 + xv.x * mul) + bs;
        m1 = (m1 + xv.y * mul) + bs;
        m2 = (m2 + xv.z * mul) + bs;
        m3 = (m3 + xv.w * mul) + bs;

        f4 sp;
        sp.x = (m0 >= vs) ? 1.0f : 0.0f;
        sp.y = (m1 >= vs) ? 1.0f : 0.0f;
        sp.z = (m2 >= vs) ? 1.0f : 0.0f;
        sp.w = (m3 >= vs) ? 1.0f : 0.0f;

        // soft reset: spike and vs are integer-valued, product exact.
        m0 -= sp.x * vs;
        m1 -= sp.y * vs;
        m2 -= sp.z * vs;
        m3 -= sp.w * vs;

        out[(size_t)t * N4 + i] = sp;
    }
}

extern "C" void kernel_launch(void* const* d_in, const int* in_sizes, int n_in,
                              void* d_out, int out_size, void* d_ws, size_t ws_size,
                              hipStream_t stream) {
    const f4*    x          = (const f4*)d_in[0];
    const float* prev_scale = (const float*)d_in[1];
    const float* prev_bias  = (const float*)d_in[2];
    const float* vth        = (const float*)d_in[3];
    const int*   tau        = (const int*)d_in[4];
    const int*   is_first   = (const int*)d_in[5];
    f4*          out        = (f4*)d_out;

    dim3 block(256);
    dim3 grid(N4 / 256);   // 4096 blocks
    IntegerNeuron_84842783965742_kernel<<<grid, block, 0, stream>>>(
        x, prev_scale, prev_bias, vth, tau, is_first, out);
}

// Round 4
// 244.990 us; speedup vs baseline: 1.0163x; 1.0127x over previous
//
#include <hip/hip_runtime.h>

// IntegerNeuron: T-step integrate-fire scan over [T,B,C,H,W].
// T=8, B=32, C=128, H=32, W=32. Memory-bound: 128 MiB in + 128 MiB out.
//
// Numerics: must be bit-exact vs the fp32 reference (hard threshold on mem).
// Reference op order:
//   drive = x * tau
//   mem   = (mem + drive) + bias_scaled
//   spike = mem >= vth_scaled
//   mem   = mem - spike * vth_scaled
// tau == 4.0 (power of two) => x*tau exact => FMA contraction of (mem + x*tau)
// is bit-identical. No reassociation at -O3 without -ffast-math.
// jnp.round == half-to-even == rintf.
//
// History:
//  R1 (#pragma preload) / R2 (empty-asm pin): VGPR stayed 24 — compiler
//    dissolved the preload at IR level; serial load->wait->compute->store
//    loop never changed. MLP theory never actually tested.
//  R3 (inline-asm loads): container crashed — outputs were "=v" (no early
//    clobber), so a load's destination tuple could alias a LATER load's
//    offset register; load0's return data could clobber o7 before load7
//    issues -> garbage address -> VM fault. Fixed here with "=&v".
//
// R4: 8 hand-written global_load_dwordx4 (SGPR base + 32-bit voffset) issued
// back-to-back, ONE s_waitcnt vmcnt(0), all in a single asm volatile with
// early-clobber outputs. Compiler cannot sink/split/remat: 8 loads in flight
// per wave instead of ~1. Slice stride = N4*16 B = 16 MiB = 0x1000000;
// max offset 7*16MiB + 16MiB < 2^27 (fits unsigned/signed 32-bit voffset).

typedef float f4 __attribute__((ext_vector_type(4)));

constexpr int T_STEPS = 8;
constexpr int NB = 32, NC = 128, NH = 32, NW = 32;
constexpr int NSP = NB * NC * NH * NW;   // 4,194,304 spatial positions
constexpr int N4  = NSP / 4;             // 1,048,576 float4 positions
constexpr int HW4 = (NH * NW) / 4;       // 256 float4 per (b,c) plane == blockDim

__global__ __launch_bounds__(256) void IntegerNeuron_84842783965742_kernel(
    const f4*    __restrict__ x,            // [T, B, C, H, W] as float4
    const float* __restrict__ prev_scale,   // [C]
    const float* __restrict__ prev_bias,    // [C]
    const float* __restrict__ vth,          // scalar
    const int*   __restrict__ tau,          // scalar int
    const int*   __restrict__ is_first,     // scalar int
    f4*          __restrict__ out)          // [T, B, C, H, W] as float4
{
    const int i = blockIdx.x * blockDim.x + threadIdx.x;   // float4 index
    const int c = blockIdx.x % NC;  // uniform per block: blockDim == HW4, so
                                    // each block is exactly one (b,c) plane.

    const float tau_f = (float)tau[0];
    const float denom = prev_scale[c] + 1e-12f;
    const float bs = rintf(prev_bias[c] * tau_f / denom);  // bias_scaled[c]
    const float vs = rintf(vth[0] * tau_f / denom);        // vth_scaled[c]
    const float mul = is_first[0] ? 1.0f : tau_f;          // drive multiplier

    const unsigned int b0 = (unsigned int)i * 16u;         // byte offset, slice 0

    // --- 8 loads back-to-back, then ONE wait. "=&v" = early-clobber: output
    // tuples can never alias offset registers (R3's crash). ---
    f4 x0, x1, x2, x3, x4, x5, x6, x7;
    asm volatile(
        "global_load_dwordx4 %[x0], %[o0], %[base]\n\t"
        "global_load_dwordx4 %[x1], %[o1], %[base]\n\t"
        "global_load_dwordx4 %[x2], %[o2], %[base]\n\t"
        "global_load_dwordx4 %[x3], %[o3], %[base]\n\t"
        "global_load_dwordx4 %[x4], %[o4], %[base]\n\t"
        "global_load_dwordx4 %[x5], %[o5], %[base]\n\t"
        "global_load_dwordx4 %[x6], %[o6], %[base]\n\t"
        "global_load_dwordx4 %[x7], %[o7], %[base]\n\t"
        "s_waitcnt vmcnt(0)"
        : [x0] "=&v"(x0), [x1] "=&v"(x1), [x2] "=&v"(x2), [x3] "=&v"(x3),
          [x4] "=&v"(x4), [x5] "=&v"(x5), [x6] "=&v"(x6), [x7] "=&v"(x7)
        : [o0] "v"(b0 + 0x0000000u), [o1] "v"(b0 + 0x1000000u),
          [o2] "v"(b0 + 0x2000000u), [o3] "v"(b0 + 0x3000000u),
          [o4] "v"(b0 + 0x4000000u), [o5] "v"(b0 + 0x5000000u),
          [o6] "v"(b0 + 0x6000000u), [o7] "v"(b0 + 0x7000000u),
          [base] "s"(x)
        : "memory");
    __builtin_amdgcn_sched_barrier(0);

    float m0 = 0.0f, m1 = 0.0f, m2 = 0.0f, m3 = 0.0f;      // mem in VGPRs

#define STEP(xv, t)                                                     \
    do {                                                                \
        /* mem = (mem + x*tau) + bias_scaled — reference association */ \
        m0 = (m0 + (xv).x * mul) + bs;                                  \
        m1 = (m1 + (xv).y * mul) + bs;                                  \
        m2 = (m2 + (xv).z * mul) + bs;                                  \
        m3 = (m3 + (xv).w * mul) + bs;                                  \
        f4 sp;                                                          \
        sp.x = (m0 >= vs) ? 1.0f : 0.0f;                                \
        sp.y = (m1 >= vs) ? 1.0f : 0.0f;                                \
        sp.z = (m2 >= vs) ? 1.0f : 0.0f;                                \
        sp.w = (m3 >= vs) ? 1.0f : 0.0f;                                \
        /* soft reset: spike and vs integer-valued, product exact */    \
        m0 -= sp.x * vs;                                                \
        m1 -= sp.y * vs;                                                \
        m2 -= sp.z * vs;                                                \
        m3 -= sp.w * vs;                                                \
        out[(size_t)(t) * N4 + i] = sp;                                 \
    } while (0)

    STEP(x0, 0);
    STEP(x1, 1);
    STEP(x2, 2);
    STEP(x3, 3);
    STEP(x4, 4);
    STEP(x5, 5);
    STEP(x6, 6);
    STEP(x7, 7);
#undef STEP
}

extern "C" void kernel_launch(void* const* d_in, const int* in_sizes, int n_in,
                              void* d_out, int out_size, void* d_ws, size_t ws_size,
                              hipStream_t stream) {
    const f4*    x          = (const f4*)d_in[0];
    const float* prev_scale = (const float*)d_in[1];
    const float* prev_bias  = (const float*)d_in[2];
    const float* vth        = (const float*)d_in[3];
    const int*   tau        = (const int*)d_in[4];
    const int*   is_first   = (const int*)d_in[5];
    f4*          out        = (f4*)d_out;

    dim3 block(256);
    dim3 grid(N4 / 256);   // 4096 blocks
    IntegerNeuron_84842783965742_kernel<<<grid, block, 0, stream>>>(
        x, prev_scale, prev_bias, vth, tau, is_first, out);
}

// Round 5
// 241.043 us; speedup vs baseline: 1.0329x; 1.0164x over previous
//
#include <hip/hip_runtime.h>

// IntegerNeuron: T-step integrate-fire scan over [T,B,C,H,W].
// T=8, B=32, C=128, H=32, W=32. Memory-bound: 128 MiB in + 128 MiB out.
//
// Numerics: must be bit-exact vs the fp32 reference (hard threshold on mem).
// Reference op order:
//   drive = x * tau
//   mem   = (mem + drive) + bias_scaled
//   spike = mem >= vth_scaled
//   mem   = mem - spike * vth_scaled
// tau == 4.0 (power of two) => x*tau exact => FMA contraction of (mem + x*tau)
// is bit-identical. No reassociation at -O3 without -ffast-math.
// jnp.round == half-to-even == rintf.
//
// History:
//  R1 (#pragma preload + __builtin_nontemporal_store): dur 85->92.5,
//    FETCH unchanged — plain `nt` does not stop L3 write-allocation.
//  R2 (empty-asm pin): null.
//  R3 (asm loads, "=v"): VM fault — output tuples aliased later loads'
//    offset regs (missing early-clobber).
//  R4 (asm loads, "=&v"): ran correct, 8 loads genuinely in flight,
//    dur 89-92 (slightly WORSE than baseline 85). ==> per-wave MLP is NOT
//    the limiter. VGPR_Count CSV field proven unreliable (reads 24 with
//    >=40 live regs); trust timing/FETCH/WRITE only.
//
// R5 theory: the limiter is memory-system service rate for the 192 MiB
// mixed traffic. FETCH is pinned at 64 MiB = half the input: the 128 MiB
// output write-allocates in the 256 MiB L3 and evicts half the (restore-
// resident) input. Stores with the stronger gfx950 policy bits `sc0 sc1 nt`
// (system-scope, no-allocate — more than R1's bare `nt`) should keep the
// output out of L3, leaving the input fully resident: FETCH -> ~0,
// HBM traffic 192 -> ~128 MiB. Everything else is the fastest-measured
// baseline structure (compiler-scheduled serial loop).
// Safety: asm stores add untracked vmem ops, which only make any compiler
// s_waitcnt vmcnt(K) stricter (more outstanding ops), never looser.

typedef float f4 __attribute__((ext_vector_type(4)));

constexpr int T_STEPS = 8;
constexpr int NB = 32, NC = 128, NH = 32, NW = 32;
constexpr int NSP = NB * NC * NH * NW;   // 4,194,304 spatial positions
constexpr int N4  = NSP / 4;             // 1,048,576 float4 positions
constexpr int HW4 = (NH * NW) / 4;       // 256 float4 per (b,c) plane == blockDim

__global__ __launch_bounds__(256) void IntegerNeuron_84842783965742_kernel(
    const f4*    __restrict__ x,            // [T, B, C, H, W] as float4
    const float* __restrict__ prev_scale,   // [C]
    const float* __restrict__ prev_bias,    // [C]
    const float* __restrict__ vth,          // scalar
    const int*   __restrict__ tau,          // scalar int
    const int*   __restrict__ is_first,    // scalar int
    f4*          __restrict__ out)          // [T, B, C, H, W] as float4
{
    const int i = blockIdx.x * blockDim.x + threadIdx.x;   // float4 index
    const int c = blockIdx.x % NC;  // uniform per block: blockDim == HW4, so
                                    // each block is exactly one (b,c) plane.

    const float tau_f = (float)tau[0];
    const float denom = prev_scale[c] + 1e-12f;
    const float bs = rintf(prev_bias[c] * tau_f / denom);  // bias_scaled[c]
    const float vs = rintf(vth[0] * tau_f / denom);        // vth_scaled[c]
    const float mul = is_first[0] ? 1.0f : tau_f;          // drive multiplier

    const unsigned int b0 = (unsigned int)i * 16u;         // byte offset, slice 0

    float m0 = 0.0f, m1 = 0.0f, m2 = 0.0f, m3 = 0.0f;      // mem in VGPRs

    #pragma unroll
    for (int t = 0; t < T_STEPS; ++t) {
        const f4 xv = x[(size_t)t * N4 + i];   // compiler-scheduled load

        // mem = (mem + x*tau) + bias_scaled  — matches reference association.
        m0 = (m0 + xv.x * mul) + bs;
        m1 = (m1 + xv.y * mul) + bs;
        m2 = (m2 + xv.z * mul) + bs;
        m3 = (m3 + xv.w * mul) + bs;

        f4 sp;
        sp.x = (m0 >= vs) ? 1.0f : 0.0f;
        sp.y = (m1 >= vs) ? 1.0f : 0.0f;
        sp.z = (m2 >= vs) ? 1.0f : 0.0f;
        sp.w = (m3 >= vs) ? 1.0f : 0.0f;

        // soft reset: spike and vs are integer-valued, product exact.
        m0 -= sp.x * vs;
        m1 -= sp.y * vs;
        m2 -= sp.z * vs;
        m3 -= sp.w * vs;

        // Store with no-allocate / system-scope policy bits: keep the output
        // stream OUT of L2/L3 so the input stays L3-resident across the
        // harness's restore->dispatch cycle. Slice stride 16 MiB = 0x1000000.
        const unsigned int ob = b0 + ((unsigned int)t << 24);
        asm volatile(
            "global_store_dwordx4 %[off], %[val], %[base] sc0 sc1 nt"
            :
            : [off] "v"(ob), [val] "v"(sp), [base] "s"(out)
            : "memory");
    }
}

extern "C" void kernel_launch(void* const* d_in, const int* in_sizes, int n_in,
                              void* d_out, int out_size, void* d_ws, size_t ws_size,
                              hipStream_t stream) {
    const f4*    x          = (const f4*)d_in[0];
    const float* prev_scale = (const float*)d_in[1];
    const float* prev_bias  = (const float*)d_in[2];
    const float* vth        = (const float*)d_in[3];
    const int*   tau        = (const int*)d_in[4];
    const int*   is_first   = (const int*)d_in[5];
    f4*          out        = (f4*)d_out;

    dim3 block(256);
    dim3 grid(N4 / 256);   // 4096 blocks
    IntegerNeuron_84842783965742_kernel<<<grid, block, 0, stream>>>(
        x, prev_scale, prev_bias, vth, tau, is_first, out);
}